// Round 1
// baseline (863.123 us; speedup 1.0000x reference)
//
#include <hip/hip_runtime.h>
#include <stdint.h>

typedef unsigned long long u64;
typedef unsigned int u32;

#define WPR 16                      // u64 words per 1024-px row
#define WORDS_PER_IMG (1024*WPR)    // 16384
#define PIXELS_PER_IMG (1024*1024)
#define HALO 33
#define OWN 64
#define BROWS (OWN + 2*HALO)        // 130

// ---------------- K1: zero the per-batch one-counts ----------------
__global__ void k_init(u32* counts) {
    if (threadIdx.x < 16) counts[threadIdx.x] = 0;
}

// ---------------- K2: bitpack target + count ones per batch ----------------
__global__ __launch_bounds__(256) void k_pack(const int* __restrict__ tgt,
                                              u64* __restrict__ bits,
                                              u32* __restrict__ counts) {
    int p = blockIdx.x * 256 + threadIdx.x;   // one pixel per thread, 16M total
    int t = tgt[p];
    u64 m = __ballot(t == 1);
    int lane = threadIdx.x & 63;
    if (lane == 0) bits[p >> 6] = m;
    __shared__ u32 bc;
    if (threadIdx.x == 0) bc = 0;
    __syncthreads();
    if (lane == 0) atomicAdd(&bc, (u32)__popcll(m));
    __syncthreads();
    if (threadIdx.x == 0) atomicAdd(&counts[p >> 20], bc);  // 1M px per batch
}

// ---------------- K3: bitwise skeletonize (32 iters, early exit) ----------------
// block = (batch, polarity, strip). Strip = 64 owned rows + 33 halo each side.
// erode OOB-neutral = 1, dilate OOB-neutral = 0 (matches SAME padding +-inf init).
__global__ __launch_bounds__(256) void k_skel(const u64* __restrict__ bits,
                                              u64* __restrict__ fore,
                                              u64* __restrict__ back) {
    __shared__ u64 bufs[3][BROWS][WPR];   // 49920 B
    __shared__ int nz;
    int bid   = blockIdx.x;
    int strip = bid & 15;
    int task  = bid >> 4;
    int batch = task >> 1;
    int pol   = task & 1;                 // 0 = fore (a), 1 = back (~a)
    int r0    = strip * OWN - HALO;
    const u64* img = bits + batch * WORDS_PER_IMG;

    u64 (*E)[WPR]  = bufs[0];
    u64 (*T1)[WPR] = bufs[1];
    u64 (*T2)[WPR] = bufs[2];

    int t = threadIdx.x;
    // load strip (invalid rows -> erode-neutral ~0)
    for (int idx = t; idx < BROWS * WPR; idx += 256) {
        int br = idx >> 4, w = idx & 15;
        int y = r0 + br;
        u64 v;
        if ((unsigned)y < 1024u) { v = img[(y << 4) + w]; if (pol) v = ~v; }
        else v = ~0ull;
        E[br][w] = v;
    }
    u64 s0 = 0, s1 = 0, s2 = 0, s3 = 0;
    __syncthreads();

    for (int k = 0; k < 32; ++k) {
        if (t == 0) nz = 0;
        // A: T1 = horizontal erode of E
        for (int idx = t; idx < BROWS * WPR; idx += 256) {
            int br = idx >> 4, w = idx & 15;
            u64 c = E[br][w];
            u64 l = w ? E[br][w - 1] : ~0ull;
            u64 r = (w < 15) ? E[br][w + 1] : ~0ull;
            T1[br][w] = c & ((c << 1) | (l >> 63)) & ((c >> 1) | (r << 63));
        }
        __syncthreads();
        // B: T2 = vertical erode of T1 (rows with invalid y forced to 0)
        u64 anyv = 0;
        for (int idx = t; idx < BROWS * WPR; idx += 256) {
            int br = idx >> 4, w = idx & 15;
            int y  = r0 + br;
            u64 v = 0;
            if ((unsigned)y < 1024u) {
                u64 a_ = (br > 0 && (unsigned)(y - 1) < 1024u) ? T1[br - 1][w] : ~0ull;
                u64 b_ = T1[br][w];
                u64 c_ = (br < BROWS - 1 && (unsigned)(y + 1) < 1024u) ? T1[br + 1][w] : ~0ull;
                v = a_ & b_ & c_;
            }
            T2[br][w] = v;
            anyv |= v;
        }
        {
            u64 bal = __ballot(anyv != 0);
            if (bal && (t & 63) == 0) atomicOr(&nz, 1);
        }
        __syncthreads();
        if (nz == 0) {
            // eroded image empty: opened = 0 forever, so s |= e_k and stop
            #pragma unroll
            for (int j = 0; j < 4; ++j) {
                int idx = t + j * 256;
                int br = HALO + (idx >> 4), w = idx & 15;
                u64 e = E[br][w];
                if (j == 0) s0 |= e; else if (j == 1) s1 |= e;
                else if (j == 2) s2 |= e; else s3 |= e;
            }
            break;
        }
        // C: T1 = horizontal dilate of T2
        for (int idx = t; idx < BROWS * WPR; idx += 256) {
            int br = idx >> 4, w = idx & 15;
            u64 c = T2[br][w];
            u64 l = w ? T2[br][w - 1] : 0ull;
            u64 r = (w < 15) ? T2[br][w + 1] : 0ull;
            T1[br][w] = c | (c << 1) | (l >> 63) | (c >> 1) | (r << 63);
        }
        __syncthreads();
        // D: opened = vertical dilate of T1 at owned rows; s |= E & ~opened
        #pragma unroll
        for (int j = 0; j < 4; ++j) {
            int idx = t + j * 256;
            int br = HALO + (idx >> 4), w = idx & 15;
            int y  = r0 + br;
            u64 a_ = ((unsigned)(y - 1) < 1024u) ? T1[br - 1][w] : 0ull;
            u64 b_ = T1[br][w];
            u64 c_ = ((unsigned)(y + 1) < 1024u) ? T1[br + 1][w] : 0ull;
            u64 add = E[br][w] & ~(a_ | b_ | c_);
            if (j == 0) s0 |= add; else if (j == 1) s1 |= add;
            else if (j == 2) s2 |= add; else s3 |= add;
        }
        // next e = eroded: swap E <-> T2
        u64 (*tmp)[WPR] = E; E = T2; T2 = tmp;
        __syncthreads();
    }

    u64* plane = (pol ? back : fore) + batch * WORDS_PER_IMG;
    #pragma unroll
    for (int j = 0; j < 4; ++j) {
        int idx = t + j * 256;
        int yo = strip * OWN + (idx >> 4);
        int w  = idx & 15;
        u64 sv = (j == 0) ? s0 : (j == 1) ? s1 : (j == 2) ? s2 : s3;
        plane[(yo << 4) + w] = sv;
    }
}

// ---------------- K4: fused loss (CE * class-weight * w_map), block partials ----------------
__global__ __launch_bounds__(256) void k_loss(const float* __restrict__ pred,
                                              const u64* __restrict__ bits,
                                              const u64* __restrict__ fore,
                                              const u64* __restrict__ back,
                                              const u32* __restrict__ counts,
                                              const int* __restrict__ epochp,
                                              float* __restrict__ partials) {
    int tid = blockIdx.x * 256 + threadIdx.x;     // 4M threads, 4 px each
    int p   = tid << 2;
    int b   = p >> 20;
    int rem = p & (PIXELS_PER_IMG - 1);
    int y   = rem >> 10;
    int x   = rem & 1023;

    const float* pb = pred + (size_t)b * (2 * PIXELS_PER_IMG);
    float4 q0 = *(const float4*)(pb + (y << 10) + x);
    float4 q1 = *(const float4*)(pb + PIXELS_PER_IMG + (y << 10) + x);

    int w  = x >> 6;
    int wi = (b << 14) + (y << 4) + w;
    u64 tw = bits[wi];
    u64 fw = fore[wi];

    // inline 3x3 dilation of back skeleton at this word
    const u64* bb = back + (b << 14);
    int rbase = y << 4;
    u64 m0 = bb[rbase + w];
    u64 mL = w ? bb[rbase + w - 1] : 0ull;
    u64 mR = (w < 15) ? bb[rbase + w + 1] : 0ull;
    if (y > 0) {
        m0 |= bb[rbase - 16 + w];
        if (w) mL |= bb[rbase - 16 + w - 1];
        if (w < 15) mR |= bb[rbase - 16 + w + 1];
    }
    if (y < 1023) {
        m0 |= bb[rbase + 16 + w];
        if (w) mL |= bb[rbase + 16 + w - 1];
        if (w < 15) mR |= bb[rbase + 16 + w + 1];
    }
    u64 dil = m0 | (m0 << 1) | (mL >> 63) | (m0 >> 1) | (mR << 63);

    float c1 = (float)counts[b];
    float c0 = (float)PIXELS_PER_IMG - c1;
    float mn = fminf(c0, c1);
    float w0 = c1 / mn, w1 = c0 / mn;   // weight for class 0 / class 1
    float factor = fminf((float)epochp[0] / 50.0f, 1.0f);

    float p0v[4] = {q0.x, q0.y, q0.z, q0.w};
    float p1v[4] = {q1.x, q1.y, q1.z, q1.w};
    int j0 = x & 63;
    float acc = 0.f;
    #pragma unroll
    for (int i = 0; i < 4; ++i) {
        int j = j0 + i;
        int tt   = (int)((tw >> j) & 1);
        float f  = (float)((fw >> j) & 1);
        float bd = (float)((dil >> j) & 1);
        float wmap = 1.0f + factor * (f + bd);
        float cw = tt ? w1 : w0;
        float d  = tt ? (p0v[i] - p1v[i]) : (p1v[i] - p0v[i]);  // p_other - p_t
        float ce = fmaxf(d, 0.0f) + log1pf(expf(-fabsf(d)));
        acc += wmap * cw * ce;
    }
    // block reduce
    for (int off = 32; off; off >>= 1) acc += __shfl_down(acc, off, 64);
    __shared__ float wsum[4];
    if ((threadIdx.x & 63) == 0) wsum[threadIdx.x >> 6] = acc;
    __syncthreads();
    if (threadIdx.x == 0)
        partials[blockIdx.x] = wsum[0] + wsum[1] + wsum[2] + wsum[3];
}

// ---------------- K5: final reduce ----------------
__global__ __launch_bounds__(256) void k_reduce(const float* __restrict__ partials,
                                                float* __restrict__ out) {
    double acc = 0.0;
    for (int i = threadIdx.x; i < 16384; i += 256) acc += (double)partials[i];
    for (int off = 32; off; off >>= 1) acc += __shfl_down(acc, off, 64);
    __shared__ double sd[4];
    if ((threadIdx.x & 63) == 0) sd[threadIdx.x >> 6] = acc;
    __syncthreads();
    if (threadIdx.x == 0)
        out[0] = (float)((sd[0] + sd[1] + sd[2] + sd[3]) / 16777216.0);
}

extern "C" void kernel_launch(void* const* d_in, const int* in_sizes, int n_in,
                              void* d_out, int out_size, void* d_ws, size_t ws_size,
                              hipStream_t stream) {
    const float* pred  = (const float*)d_in[0];
    const int*   target = (const int*)d_in[1];
    const int*   epoch  = (const int*)d_in[2];

    char* ws = (char*)d_ws;
    u32*   counts   = (u32*)ws;                    // 64 B
    float* partials = (float*)(ws + 4096);         // 64 KB
    u64*   bits     = (u64*)(ws + (1u << 20));     // 2 MB
    u64*   fore     = (u64*)(ws + (3u << 20));     // 2 MB
    u64*   back     = (u64*)(ws + (5u << 20));     // 2 MB  (7 MB total)

    hipLaunchKernelGGL(k_init,   dim3(1),     dim3(64),  0, stream, counts);
    hipLaunchKernelGGL(k_pack,   dim3(65536), dim3(256), 0, stream, target, bits, counts);
    hipLaunchKernelGGL(k_skel,   dim3(512),   dim3(256), 0, stream, bits, fore, back);
    hipLaunchKernelGGL(k_loss,   dim3(16384), dim3(256), 0, stream, pred, bits, fore, back,
                       counts, epoch, partials);
    hipLaunchKernelGGL(k_reduce, dim3(1),     dim3(256), 0, stream, partials, (float*)d_out);
}

// Round 2
// 116.038 us; speedup vs baseline: 7.4383x; 7.4383x over previous
//
#include <hip/hip_runtime.h>
#include <stdint.h>

typedef unsigned long long u64;
typedef unsigned int u32;

#define WPR 16                      // u64 words per 1024-px row
#define WORDS_PER_IMG (1024*WPR)    // 16384
#define PIXELS_PER_IMG (1024*1024)
#define HALO 33
#define OWN 64
#define BROWS (OWN + 2*HALO)        // 130

// ---------------- K2: bitpack target + per-block one-count partials ----------------
// Each wave: 1024 consecutive pixels (16 coalesced dword loads + 16 ballots).
// Each block (4 waves): 4096 px, entirely within one batch. NO global atomics.
__global__ __launch_bounds__(256) void k_pack(const int* __restrict__ tgt,
                                              u64* __restrict__ bits,
                                              u32* __restrict__ cpart) {
    int gwave = (blockIdx.x * 256 + threadIdx.x) >> 6;   // 16384 waves
    int lane  = threadIdx.x & 63;
    int base  = gwave << 10;                             // pixel base of this wave
    u32 cnt = 0;
    u64 wsel = 0;
    #pragma unroll
    for (int j = 0; j < 16; ++j) {
        int t = tgt[base + (j << 6) + lane];
        u64 m = __ballot(t == 1);
        cnt += (t == 1);
        if (lane == j) wsel = m;       // j is compile-time in unrolled loop
    }
    if (lane < 16) bits[(base >> 6) + lane] = wsel;      // 128B coalesced store

    // block reduce of cnt -> one partial per block
    for (int off = 32; off; off >>= 1) cnt += __shfl_down(cnt, off, 64);
    __shared__ u32 ws_[4];
    if ((threadIdx.x & 63) == 0) ws_[threadIdx.x >> 6] = cnt;
    __syncthreads();
    if (threadIdx.x == 0)
        cpart[blockIdx.x] = ws_[0] + ws_[1] + ws_[2] + ws_[3];
}

// ---------------- K2b: sum 256 partials per batch -> counts[16] ----------------
__global__ __launch_bounds__(256) void k_cnt(const u32* __restrict__ cpart,
                                             u32* __restrict__ counts) {
    int b = blockIdx.x;
    u32 v = cpart[(b << 8) + threadIdx.x];
    for (int off = 32; off; off >>= 1) v += __shfl_down(v, off, 64);
    __shared__ u32 s[4];
    if ((threadIdx.x & 63) == 0) s[threadIdx.x >> 6] = v;
    __syncthreads();
    if (threadIdx.x == 0) counts[b] = s[0] + s[1] + s[2] + s[3];
}

// ---------------- K3: bitwise skeletonize (32 iters, early exit) ----------------
__global__ __launch_bounds__(256) void k_skel(const u64* __restrict__ bits,
                                              u64* __restrict__ fore,
                                              u64* __restrict__ back) {
    __shared__ u64 bufs[3][BROWS][WPR];   // 49920 B
    __shared__ int nz;
    int bid   = blockIdx.x;
    int strip = bid & 15;
    int task  = bid >> 4;
    int batch = task >> 1;
    int pol   = task & 1;                 // 0 = fore (a), 1 = back (~a)
    int r0    = strip * OWN - HALO;
    const u64* img = bits + batch * WORDS_PER_IMG;

    u64 (*E)[WPR]  = bufs[0];
    u64 (*T1)[WPR] = bufs[1];
    u64 (*T2)[WPR] = bufs[2];

    int t = threadIdx.x;
    for (int idx = t; idx < BROWS * WPR; idx += 256) {
        int br = idx >> 4, w = idx & 15;
        int y = r0 + br;
        u64 v;
        if ((unsigned)y < 1024u) { v = img[(y << 4) + w]; if (pol) v = ~v; }
        else v = ~0ull;
        E[br][w] = v;
    }
    u64 s0 = 0, s1 = 0, s2 = 0, s3 = 0;
    __syncthreads();

    for (int k = 0; k < 32; ++k) {
        if (t == 0) nz = 0;
        // A: T1 = horizontal erode of E
        for (int idx = t; idx < BROWS * WPR; idx += 256) {
            int br = idx >> 4, w = idx & 15;
            u64 c = E[br][w];
            u64 l = w ? E[br][w - 1] : ~0ull;
            u64 r = (w < 15) ? E[br][w + 1] : ~0ull;
            T1[br][w] = c & ((c << 1) | (l >> 63)) & ((c >> 1) | (r << 63));
        }
        __syncthreads();
        // B: T2 = vertical erode of T1
        u64 anyv = 0;
        for (int idx = t; idx < BROWS * WPR; idx += 256) {
            int br = idx >> 4, w = idx & 15;
            int y  = r0 + br;
            u64 v = 0;
            if ((unsigned)y < 1024u) {
                u64 a_ = (br > 0 && (unsigned)(y - 1) < 1024u) ? T1[br - 1][w] : ~0ull;
                u64 b_ = T1[br][w];
                u64 c_ = (br < BROWS - 1 && (unsigned)(y + 1) < 1024u) ? T1[br + 1][w] : ~0ull;
                v = a_ & b_ & c_;
            }
            T2[br][w] = v;
            anyv |= v;
        }
        {
            u64 bal = __ballot(anyv != 0);
            if (bal && (t & 63) == 0) atomicOr(&nz, 1);
        }
        __syncthreads();
        if (nz == 0) {
            #pragma unroll
            for (int j = 0; j < 4; ++j) {
                int idx = t + j * 256;
                int br = HALO + (idx >> 4), w = idx & 15;
                u64 e = E[br][w];
                if (j == 0) s0 |= e; else if (j == 1) s1 |= e;
                else if (j == 2) s2 |= e; else s3 |= e;
            }
            break;
        }
        // C: T1 = horizontal dilate of T2
        for (int idx = t; idx < BROWS * WPR; idx += 256) {
            int br = idx >> 4, w = idx & 15;
            u64 c = T2[br][w];
            u64 l = w ? T2[br][w - 1] : 0ull;
            u64 r = (w < 15) ? T2[br][w + 1] : 0ull;
            T1[br][w] = c | (c << 1) | (l >> 63) | (c >> 1) | (r << 63);
        }
        __syncthreads();
        // D: opened = vertical dilate of T1 at owned rows; s |= E & ~opened
        #pragma unroll
        for (int j = 0; j < 4; ++j) {
            int idx = t + j * 256;
            int br = HALO + (idx >> 4), w = idx & 15;
            int y  = r0 + br;
            u64 a_ = ((unsigned)(y - 1) < 1024u) ? T1[br - 1][w] : 0ull;
            u64 b_ = T1[br][w];
            u64 c_ = ((unsigned)(y + 1) < 1024u) ? T1[br + 1][w] : 0ull;
            u64 add = E[br][w] & ~(a_ | b_ | c_);
            if (j == 0) s0 |= add; else if (j == 1) s1 |= add;
            else if (j == 2) s2 |= add; else s3 |= add;
        }
        u64 (*tmp)[WPR] = E; E = T2; T2 = tmp;
        __syncthreads();
    }

    u64* plane = (pol ? back : fore) + batch * WORDS_PER_IMG;
    #pragma unroll
    for (int j = 0; j < 4; ++j) {
        int idx = t + j * 256;
        int yo = strip * OWN + (idx >> 4);
        int w  = idx & 15;
        u64 sv = (j == 0) ? s0 : (j == 1) ? s1 : (j == 2) ? s2 : s3;
        plane[(yo << 4) + w] = sv;
    }
}

// ---------------- K4: fused loss ----------------
__global__ __launch_bounds__(256) void k_loss(const float* __restrict__ pred,
                                              const u64* __restrict__ bits,
                                              const u64* __restrict__ fore,
                                              const u64* __restrict__ back,
                                              const u32* __restrict__ counts,
                                              const int* __restrict__ epochp,
                                              float* __restrict__ partials) {
    int tid = blockIdx.x * 256 + threadIdx.x;     // 4M threads, 4 px each
    int p   = tid << 2;
    int b   = p >> 20;
    int rem = p & (PIXELS_PER_IMG - 1);
    int y   = rem >> 10;
    int x   = rem & 1023;

    const float* pb = pred + (size_t)b * (2 * PIXELS_PER_IMG);
    float4 q0 = *(const float4*)(pb + (y << 10) + x);
    float4 q1 = *(const float4*)(pb + PIXELS_PER_IMG + (y << 10) + x);

    int w  = x >> 6;
    int wi = (b << 14) + (y << 4) + w;
    u64 tw = bits[wi];
    u64 fw = fore[wi];

    // inline 3x3 dilation of back skeleton at this word
    const u64* bb = back + (b << 14);
    int rbase = y << 4;
    u64 m0 = bb[rbase + w];
    u64 mL = w ? bb[rbase + w - 1] : 0ull;
    u64 mR = (w < 15) ? bb[rbase + w + 1] : 0ull;
    if (y > 0) {
        m0 |= bb[rbase - 16 + w];
        if (w) mL |= bb[rbase - 16 + w - 1];
        if (w < 15) mR |= bb[rbase - 16 + w + 1];
    }
    if (y < 1023) {
        m0 |= bb[rbase + 16 + w];
        if (w) mL |= bb[rbase + 16 + w - 1];
        if (w < 15) mR |= bb[rbase + 16 + w + 1];
    }
    u64 dil = m0 | (m0 << 1) | (mL >> 63) | (m0 >> 1) | (mR << 63);

    float c1 = (float)counts[b];
    float c0 = (float)PIXELS_PER_IMG - c1;
    float mn = fminf(c0, c1);
    float w0 = c1 / mn, w1 = c0 / mn;   // weight for class 0 / class 1
    float factor = fminf((float)epochp[0] / 50.0f, 1.0f);

    float p0v[4] = {q0.x, q0.y, q0.z, q0.w};
    float p1v[4] = {q1.x, q1.y, q1.z, q1.w};
    int j0 = x & 63;
    float acc = 0.f;
    #pragma unroll
    for (int i = 0; i < 4; ++i) {
        int j = j0 + i;
        int tt   = (int)((tw >> j) & 1);
        float f  = (float)((fw >> j) & 1);
        float bd = (float)((dil >> j) & 1);
        float wmap = 1.0f + factor * (f + bd);
        float cw = tt ? w1 : w0;
        float d  = tt ? (p0v[i] - p1v[i]) : (p1v[i] - p0v[i]);  // p_other - p_t
        float ce = fmaxf(d, 0.0f) + log1pf(expf(-fabsf(d)));
        acc += wmap * cw * ce;
    }
    for (int off = 32; off; off >>= 1) acc += __shfl_down(acc, off, 64);
    __shared__ float wsum[4];
    if ((threadIdx.x & 63) == 0) wsum[threadIdx.x >> 6] = acc;
    __syncthreads();
    if (threadIdx.x == 0)
        partials[blockIdx.x] = wsum[0] + wsum[1] + wsum[2] + wsum[3];
}

// ---------------- K5: final reduce ----------------
__global__ __launch_bounds__(256) void k_reduce(const float* __restrict__ partials,
                                                float* __restrict__ out) {
    double acc = 0.0;
    for (int i = threadIdx.x; i < 16384; i += 256) acc += (double)partials[i];
    for (int off = 32; off; off >>= 1) acc += __shfl_down(acc, off, 64);
    __shared__ double sd[4];
    if ((threadIdx.x & 63) == 0) sd[threadIdx.x >> 6] = acc;
    __syncthreads();
    if (threadIdx.x == 0)
        out[0] = (float)((sd[0] + sd[1] + sd[2] + sd[3]) / 16777216.0);
}

extern "C" void kernel_launch(void* const* d_in, const int* in_sizes, int n_in,
                              void* d_out, int out_size, void* d_ws, size_t ws_size,
                              hipStream_t stream) {
    const float* pred   = (const float*)d_in[0];
    const int*   target = (const int*)d_in[1];
    const int*   epoch  = (const int*)d_in[2];

    char* ws = (char*)d_ws;
    u32*   counts   = (u32*)ws;                    // 64 B
    u32*   cpart    = (u32*)(ws + 1024);           // 16 KB (4096 u32)
    float* partials = (float*)(ws + (1u << 17));   // 64 KB @ 128K
    u64*   bits     = (u64*)(ws + (1u << 20));     // 2 MB
    u64*   fore     = (u64*)(ws + (3u << 20));     // 2 MB
    u64*   back     = (u64*)(ws + (5u << 20));     // 2 MB  (7 MB total)

    hipLaunchKernelGGL(k_pack,   dim3(4096),  dim3(256), 0, stream, target, bits, cpart);
    hipLaunchKernelGGL(k_cnt,    dim3(16),    dim3(256), 0, stream, cpart, counts);
    hipLaunchKernelGGL(k_skel,   dim3(512),   dim3(256), 0, stream, bits, fore, back);
    hipLaunchKernelGGL(k_loss,   dim3(16384), dim3(256), 0, stream, pred, bits, fore, back,
                       counts, epoch, partials);
    hipLaunchKernelGGL(k_reduce, dim3(1),     dim3(256), 0, stream, partials, (float*)d_out);
}

// Round 3
// 67.535 us; speedup vs baseline: 12.7803x; 1.7182x over previous
//
#include <hip/hip_runtime.h>
#include <stdint.h>

typedef unsigned long long u64;
typedef unsigned int u32;

#define WPR 16                      // u64 words per 1024-px row
#define WORDS_PER_IMG (1024*WPR)    // 16384
#define PIXELS_PER_IMG (1024*1024)
#define HALO 33
#define OWN 64
#define BROWS (OWN + 2*HALO)        // 130

// ---------------- K2: bitpack target + per-block one-count partials ----------------
__global__ __launch_bounds__(256) void k_pack(const int* __restrict__ tgt,
                                              u64* __restrict__ bits,
                                              u32* __restrict__ cpart) {
    int gwave = (blockIdx.x * 256 + threadIdx.x) >> 6;   // 16384 waves
    int lane  = threadIdx.x & 63;
    int base  = gwave << 10;                             // pixel base of this wave
    u32 cnt = 0;
    u64 wsel = 0;
    #pragma unroll
    for (int j = 0; j < 16; ++j) {
        int t = tgt[base + (j << 6) + lane];
        u64 m = __ballot(t == 1);
        cnt += (t == 1);
        if (lane == j) wsel = m;
    }
    if (lane < 16) bits[(base >> 6) + lane] = wsel;

    for (int off = 32; off; off >>= 1) cnt += __shfl_down(cnt, off, 64);
    __shared__ u32 ws_[4];
    if ((threadIdx.x & 63) == 0) ws_[threadIdx.x >> 6] = cnt;
    __syncthreads();
    if (threadIdx.x == 0)
        cpart[blockIdx.x] = ws_[0] + ws_[1] + ws_[2] + ws_[3];
}

// ---------------- K2b: sum 256 partials per batch -> counts[16] ----------------
__global__ __launch_bounds__(256) void k_cnt(const u32* __restrict__ cpart,
                                             u32* __restrict__ counts) {
    int b = blockIdx.x;
    u32 v = cpart[(b << 8) + threadIdx.x];
    for (int off = 32; off; off >>= 1) v += __shfl_down(v, off, 64);
    __shared__ u32 s[4];
    if ((threadIdx.x & 63) == 0) s[threadIdx.x >> 6] = v;
    __syncthreads();
    if (threadIdx.x == 0) counts[b] = s[0] + s[1] + s[2] + s[3];
}

// ---------------- K3: bitwise skeletonize (32 iters, early exit) ----------------
__global__ __launch_bounds__(256) void k_skel(const u64* __restrict__ bits,
                                              u64* __restrict__ fore,
                                              u64* __restrict__ back) {
    __shared__ u64 bufs[3][BROWS][WPR];   // 49920 B
    __shared__ int nz;
    int bid   = blockIdx.x;
    int strip = bid & 15;
    int task  = bid >> 4;
    int batch = task >> 1;
    int pol   = task & 1;                 // 0 = fore (a), 1 = back (~a)
    int r0    = strip * OWN - HALO;
    const u64* img = bits + batch * WORDS_PER_IMG;

    u64 (*E)[WPR]  = bufs[0];
    u64 (*T1)[WPR] = bufs[1];
    u64 (*T2)[WPR] = bufs[2];

    int t = threadIdx.x;
    for (int idx = t; idx < BROWS * WPR; idx += 256) {
        int br = idx >> 4, w = idx & 15;
        int y = r0 + br;
        u64 v;
        if ((unsigned)y < 1024u) { v = img[(y << 4) + w]; if (pol) v = ~v; }
        else v = ~0ull;
        E[br][w] = v;
    }
    u64 s0 = 0, s1 = 0, s2 = 0, s3 = 0;
    __syncthreads();

    for (int k = 0; k < 32; ++k) {
        if (t == 0) nz = 0;
        // A: T1 = horizontal erode of E
        for (int idx = t; idx < BROWS * WPR; idx += 256) {
            int br = idx >> 4, w = idx & 15;
            u64 c = E[br][w];
            u64 l = w ? E[br][w - 1] : ~0ull;
            u64 r = (w < 15) ? E[br][w + 1] : ~0ull;
            T1[br][w] = c & ((c << 1) | (l >> 63)) & ((c >> 1) | (r << 63));
        }
        __syncthreads();
        // B: T2 = vertical erode of T1
        u64 anyv = 0;
        for (int idx = t; idx < BROWS * WPR; idx += 256) {
            int br = idx >> 4, w = idx & 15;
            int y  = r0 + br;
            u64 v = 0;
            if ((unsigned)y < 1024u) {
                u64 a_ = (br > 0 && (unsigned)(y - 1) < 1024u) ? T1[br - 1][w] : ~0ull;
                u64 b_ = T1[br][w];
                u64 c_ = (br < BROWS - 1 && (unsigned)(y + 1) < 1024u) ? T1[br + 1][w] : ~0ull;
                v = a_ & b_ & c_;
            }
            T2[br][w] = v;
            anyv |= v;
        }
        {
            u64 bal = __ballot(anyv != 0);
            if (bal && (t & 63) == 0) atomicOr(&nz, 1);
        }
        __syncthreads();
        if (nz == 0) {
            #pragma unroll
            for (int j = 0; j < 4; ++j) {
                int idx = t + j * 256;
                int br = HALO + (idx >> 4), w = idx & 15;
                u64 e = E[br][w];
                if (j == 0) s0 |= e; else if (j == 1) s1 |= e;
                else if (j == 2) s2 |= e; else s3 |= e;
            }
            break;
        }
        // C: T1 = horizontal dilate of T2
        for (int idx = t; idx < BROWS * WPR; idx += 256) {
            int br = idx >> 4, w = idx & 15;
            u64 c = T2[br][w];
            u64 l = w ? T2[br][w - 1] : 0ull;
            u64 r = (w < 15) ? T2[br][w + 1] : 0ull;
            T1[br][w] = c | (c << 1) | (l >> 63) | (c >> 1) | (r << 63);
        }
        __syncthreads();
        // D: opened = vertical dilate of T1 at owned rows; s |= E & ~opened
        #pragma unroll
        for (int j = 0; j < 4; ++j) {
            int idx = t + j * 256;
            int br = HALO + (idx >> 4), w = idx & 15;
            int y  = r0 + br;
            u64 a_ = ((unsigned)(y - 1) < 1024u) ? T1[br - 1][w] : 0ull;
            u64 b_ = T1[br][w];
            u64 c_ = ((unsigned)(y + 1) < 1024u) ? T1[br + 1][w] : 0ull;
            u64 add = E[br][w] & ~(a_ | b_ | c_);
            if (j == 0) s0 |= add; else if (j == 1) s1 |= add;
            else if (j == 2) s2 |= add; else s3 |= add;
        }
        u64 (*tmp)[WPR] = E; E = T2; T2 = tmp;
        __syncthreads();
    }

    u64* plane = (pol ? back : fore) + batch * WORDS_PER_IMG;
    #pragma unroll
    for (int j = 0; j < 4; ++j) {
        int idx = t + j * 256;
        int yo = strip * OWN + (idx >> 4);
        int w  = idx & 15;
        u64 sv = (j == 0) ? s0 : (j == 1) ? s1 : (j == 2) ? s2 : s3;
        plane[(yo << 4) + w] = sv;
    }
}

// ---------------- K4: fused loss, 8 px/thread, fast softplus ----------------
__global__ __launch_bounds__(256) void k_loss(const float* __restrict__ pred,
                                              const u64* __restrict__ bits,
                                              const u64* __restrict__ fore,
                                              const u64* __restrict__ back,
                                              const u32* __restrict__ counts,
                                              const int* __restrict__ epochp,
                                              float* __restrict__ partials) {
    const float LOG2E = 1.4426950408889634f;
    const float LN2   = 0.6931471805599453f;

    int tid = blockIdx.x * 256 + threadIdx.x;     // 2M threads, 8 px each
    int p   = tid << 3;
    int b   = p >> 20;
    int rem = p & (PIXELS_PER_IMG - 1);
    int y   = rem >> 10;
    int x   = rem & 1023;                          // multiple of 8

    const float* pb = pred + (size_t)b * (2 * PIXELS_PER_IMG);
    const float* r0p = pb + (y << 10) + x;
    const float* r1p = pb + PIXELS_PER_IMG + (y << 10) + x;
    float4 q0a = *(const float4*)(r0p);
    float4 q0b = *(const float4*)(r0p + 4);
    float4 q1a = *(const float4*)(r1p);
    float4 q1b = *(const float4*)(r1p + 4);

    int w  = x >> 6;
    int wi = (b << 14) + (y << 4) + w;
    u64 tw = bits[wi];
    u64 fw = fore[wi];

    // inline 3x3 dilation of back skeleton at this word
    const u64* bb = back + (b << 14);
    int rbase = y << 4;
    u64 m0 = bb[rbase + w];
    u64 mL = w ? bb[rbase + w - 1] : 0ull;
    u64 mR = (w < 15) ? bb[rbase + w + 1] : 0ull;
    if (y > 0) {
        m0 |= bb[rbase - 16 + w];
        if (w) mL |= bb[rbase - 16 + w - 1];
        if (w < 15) mR |= bb[rbase - 16 + w + 1];
    }
    if (y < 1023) {
        m0 |= bb[rbase + 16 + w];
        if (w) mL |= bb[rbase + 16 + w - 1];
        if (w < 15) mR |= bb[rbase + 16 + w + 1];
    }
    u64 dil = m0 | (m0 << 1) | (mL >> 63) | (m0 >> 1) | (mR << 63);

    float c1 = (float)counts[b];
    float c0 = (float)PIXELS_PER_IMG - c1;
    float mn = fminf(c0, c1);
    float rmn = __builtin_amdgcn_rcpf(mn);
    float w0 = c1 * rmn, w1 = c0 * rmn;   // class weight for class 0 / 1
    float factor = fminf((float)epochp[0] / 50.0f, 1.0f);

    int j0 = x & 63;                                // multiple of 8
    u32 t8 = (u32)(tw  >> j0) & 255u;
    u32 f8 = (u32)(fw  >> j0) & 255u;
    u32 b8 = (u32)(dil >> j0) & 255u;

    float p0v[8] = {q0a.x, q0a.y, q0a.z, q0a.w, q0b.x, q0b.y, q0b.z, q0b.w};
    float p1v[8] = {q1a.x, q1a.y, q1a.z, q1a.w, q1b.x, q1b.y, q1b.z, q1b.w};

    float acc = 0.f;
    #pragma unroll
    for (int i = 0; i < 8; ++i) {
        u32 tt = (t8 >> i) & 1u;
        float fb = (float)(((f8 >> i) & 1u) + ((b8 >> i) & 1u));
        float wmap = 1.0f + factor * fb;
        float cw = tt ? w1 : w0;
        float diff  = p1v[i] - p0v[i];
        float adiff = fabsf(diff);
        // softplus(d), d = +-diff: max(d,0)+log1p(exp(-|d|))
        //   = 0.5*|diff| + ln2*log2(1+exp2(-|diff|*log2e)) + (tt ? -0.5 : 0.5)*diff
        float T = LN2 * __builtin_amdgcn_logf(1.0f + __builtin_amdgcn_exp2f(-adiff * LOG2E));
        float ce = fmaf(tt ? -0.5f : 0.5f, diff, fmaf(0.5f, adiff, T));
        acc = fmaf(wmap * cw, ce, acc);
    }
    for (int off = 32; off; off >>= 1) acc += __shfl_down(acc, off, 64);
    __shared__ float wsum[4];
    if ((threadIdx.x & 63) == 0) wsum[threadIdx.x >> 6] = acc;
    __syncthreads();
    if (threadIdx.x == 0)
        partials[blockIdx.x] = wsum[0] + wsum[1] + wsum[2] + wsum[3];
}

// ---------------- K5: final reduce (8192 partials) ----------------
__global__ __launch_bounds__(256) void k_reduce(const float* __restrict__ partials,
                                                float* __restrict__ out) {
    double acc = 0.0;
    for (int i = threadIdx.x; i < 8192; i += 256) acc += (double)partials[i];
    for (int off = 32; off; off >>= 1) acc += __shfl_down(acc, off, 64);
    __shared__ double sd[4];
    if ((threadIdx.x & 63) == 0) sd[threadIdx.x >> 6] = acc;
    __syncthreads();
    if (threadIdx.x == 0)
        out[0] = (float)((sd[0] + sd[1] + sd[2] + sd[3]) / 16777216.0);
}

extern "C" void kernel_launch(void* const* d_in, const int* in_sizes, int n_in,
                              void* d_out, int out_size, void* d_ws, size_t ws_size,
                              hipStream_t stream) {
    const float* pred   = (const float*)d_in[0];
    const int*   target = (const int*)d_in[1];
    const int*   epoch  = (const int*)d_in[2];

    char* ws = (char*)d_ws;
    u32*   counts   = (u32*)ws;                    // 64 B
    u32*   cpart    = (u32*)(ws + 1024);           // 16 KB
    float* partials = (float*)(ws + (1u << 17));   // 32 KB @ 128K
    u64*   bits     = (u64*)(ws + (1u << 20));     // 2 MB
    u64*   fore     = (u64*)(ws + (3u << 20));     // 2 MB
    u64*   back     = (u64*)(ws + (5u << 20));     // 2 MB

    hipLaunchKernelGGL(k_pack,   dim3(4096), dim3(256), 0, stream, target, bits, cpart);
    hipLaunchKernelGGL(k_cnt,    dim3(16),   dim3(256), 0, stream, cpart, counts);
    hipLaunchKernelGGL(k_skel,   dim3(512),  dim3(256), 0, stream, bits, fore, back);
    hipLaunchKernelGGL(k_loss,   dim3(8192), dim3(256), 0, stream, pred, bits, fore, back,
                       counts, epoch, partials);
    hipLaunchKernelGGL(k_reduce, dim3(1),    dim3(256), 0, stream, partials, (float*)d_out);
}

// Round 4
// 66.205 us; speedup vs baseline: 13.0371x; 1.0201x over previous
//
#include <hip/hip_runtime.h>
#include <stdint.h>

typedef unsigned long long u64;
typedef unsigned int u32;
typedef unsigned short u16;

#define WPR 16                      // u64 words per 1024-px row
#define WORDS_PER_IMG (1024*WPR)    // 16384
#define PIXELS_PER_IMG (1024*1024)
#define HALO 33
#define OWN 64
#define BROWS (OWN + 2*HALO)        // 130

// ---------------- K2: bitpack target (16 px/thread, int4 loads) ----------------
// 4096 blocks x 256 threads; block covers 4096 px = 64 u64 words.
__global__ __launch_bounds__(256) void k_pack(const int* __restrict__ tgt,
                                              u64* __restrict__ bits,
                                              u32* __restrict__ cpart) {
    __shared__ u16 marr[256];       // 16-bit mask per thread
    __shared__ u32 ws_[4];
    int t = threadIdx.x;
    const int4* p4 = (const int4*)(tgt + ((size_t)blockIdx.x * 256 + t) * 16);
    u32 m16 = 0;
    #pragma unroll
    for (int k = 0; k < 4; ++k) {
        int4 v = p4[k];
        m16 |= (u32)(v.x & 1) << (4 * k + 0);
        m16 |= (u32)(v.y & 1) << (4 * k + 1);
        m16 |= (u32)(v.z & 1) << (4 * k + 2);
        m16 |= (u32)(v.w & 1) << (4 * k + 3);
    }
    marr[t] = (u16)m16;
    u32 cnt = __popc(m16);
    for (int off = 32; off; off >>= 1) cnt += __shfl_down(cnt, off, 64);
    if ((t & 63) == 0) ws_[t >> 6] = cnt;
    __syncthreads();
    if (t < 64)                      // little-endian: marr[4t..4t+3] IS the u64
        bits[(size_t)blockIdx.x * 64 + t] = ((const u64*)marr)[t];
    if (t == 0) cpart[blockIdx.x] = ws_[0] + ws_[1] + ws_[2] + ws_[3];
}

// ---------------- K3: bitwise skeletonize (32 iters, early exit) ----------------
__global__ __launch_bounds__(256) void k_skel(const u64* __restrict__ bits,
                                              u64* __restrict__ fore,
                                              u64* __restrict__ back) {
    __shared__ u64 bufs[3][BROWS][WPR];   // 49920 B
    __shared__ int nz;
    int bid   = blockIdx.x;
    int strip = bid & 15;
    int task  = bid >> 4;
    int batch = task >> 1;
    int pol   = task & 1;                 // 0 = fore (a), 1 = back (~a)
    int r0    = strip * OWN - HALO;
    const u64* img = bits + batch * WORDS_PER_IMG;

    u64 (*E)[WPR]  = bufs[0];
    u64 (*T1)[WPR] = bufs[1];
    u64 (*T2)[WPR] = bufs[2];

    int t = threadIdx.x;
    for (int idx = t; idx < BROWS * WPR; idx += 256) {
        int br = idx >> 4, w = idx & 15;
        int y = r0 + br;
        u64 v;
        if ((unsigned)y < 1024u) { v = img[(y << 4) + w]; if (pol) v = ~v; }
        else v = ~0ull;
        E[br][w] = v;
    }
    u64 s0 = 0, s1 = 0, s2 = 0, s3 = 0;
    __syncthreads();

    for (int k = 0; k < 32; ++k) {
        if (t == 0) nz = 0;
        // A: T1 = horizontal erode of E
        for (int idx = t; idx < BROWS * WPR; idx += 256) {
            int br = idx >> 4, w = idx & 15;
            u64 c = E[br][w];
            u64 l = w ? E[br][w - 1] : ~0ull;
            u64 r = (w < 15) ? E[br][w + 1] : ~0ull;
            T1[br][w] = c & ((c << 1) | (l >> 63)) & ((c >> 1) | (r << 63));
        }
        __syncthreads();
        // B: T2 = vertical erode of T1
        u64 anyv = 0;
        for (int idx = t; idx < BROWS * WPR; idx += 256) {
            int br = idx >> 4, w = idx & 15;
            int y  = r0 + br;
            u64 v = 0;
            if ((unsigned)y < 1024u) {
                u64 a_ = (br > 0 && (unsigned)(y - 1) < 1024u) ? T1[br - 1][w] : ~0ull;
                u64 b_ = T1[br][w];
                u64 c_ = (br < BROWS - 1 && (unsigned)(y + 1) < 1024u) ? T1[br + 1][w] : ~0ull;
                v = a_ & b_ & c_;
            }
            T2[br][w] = v;
            anyv |= v;
        }
        {
            u64 bal = __ballot(anyv != 0);
            if (bal && (t & 63) == 0) atomicOr(&nz, 1);
        }
        __syncthreads();
        if (nz == 0) {
            #pragma unroll
            for (int j = 0; j < 4; ++j) {
                int idx = t + j * 256;
                int br = HALO + (idx >> 4), w = idx & 15;
                u64 e = E[br][w];
                if (j == 0) s0 |= e; else if (j == 1) s1 |= e;
                else if (j == 2) s2 |= e; else s3 |= e;
            }
            break;
        }
        // C: T1 = horizontal dilate of T2
        for (int idx = t; idx < BROWS * WPR; idx += 256) {
            int br = idx >> 4, w = idx & 15;
            u64 c = T2[br][w];
            u64 l = w ? T2[br][w - 1] : 0ull;
            u64 r = (w < 15) ? T2[br][w + 1] : 0ull;
            T1[br][w] = c | (c << 1) | (l >> 63) | (c >> 1) | (r << 63);
        }
        __syncthreads();
        // D: opened = vertical dilate of T1 at owned rows; s |= E & ~opened
        #pragma unroll
        for (int j = 0; j < 4; ++j) {
            int idx = t + j * 256;
            int br = HALO + (idx >> 4), w = idx & 15;
            int y  = r0 + br;
            u64 a_ = ((unsigned)(y - 1) < 1024u) ? T1[br - 1][w] : 0ull;
            u64 b_ = T1[br][w];
            u64 c_ = ((unsigned)(y + 1) < 1024u) ? T1[br + 1][w] : 0ull;
            u64 add = E[br][w] & ~(a_ | b_ | c_);
            if (j == 0) s0 |= add; else if (j == 1) s1 |= add;
            else if (j == 2) s2 |= add; else s3 |= add;
        }
        u64 (*tmp)[WPR] = E; E = T2; T2 = tmp;
        __syncthreads();
    }

    u64* plane = (pol ? back : fore) + batch * WORDS_PER_IMG;
    #pragma unroll
    for (int j = 0; j < 4; ++j) {
        int idx = t + j * 256;
        int yo = strip * OWN + (idx >> 4);
        int w  = idx & 15;
        u64 sv = (j == 0) ? s0 : (j == 1) ? s1 : (j == 2) ? s2 : s3;
        plane[(yo << 4) + w] = sv;
    }
}

// ---------------- K4: fused loss, 8 px/thread, count preamble ----------------
__global__ __launch_bounds__(256) void k_loss(const float* __restrict__ pred,
                                              const u64* __restrict__ bits,
                                              const u64* __restrict__ fore,
                                              const u64* __restrict__ back,
                                              const u32* __restrict__ cpart,
                                              const int* __restrict__ epochp,
                                              float* __restrict__ partials) {
    const float LOG2E = 1.4426950408889634f;
    const float LN2   = 0.6931471805599453f;

    int b = blockIdx.x >> 9;                       // 512 blocks per batch

    // preamble: batch one-count from the 256 k_pack partials (L2-hit)
    __shared__ u32 cs[4];
    __shared__ float s_c1;
    {
        u32 v = cpart[(b << 8) + threadIdx.x];
        for (int off = 32; off; off >>= 1) v += __shfl_down(v, off, 64);
        if ((threadIdx.x & 63) == 0) cs[threadIdx.x >> 6] = v;
        __syncthreads();
        if (threadIdx.x == 0) s_c1 = (float)(cs[0] + cs[1] + cs[2] + cs[3]);
        __syncthreads();
    }

    int tid = blockIdx.x * 256 + threadIdx.x;     // 2M threads, 8 px each
    int p   = tid << 3;
    int rem = p & (PIXELS_PER_IMG - 1);
    int y   = rem >> 10;
    int x   = rem & 1023;                          // multiple of 8

    const float* pb = pred + (size_t)b * (2 * PIXELS_PER_IMG);
    const float* r0p = pb + (y << 10) + x;
    const float* r1p = pb + PIXELS_PER_IMG + (y << 10) + x;
    float4 q0a = *(const float4*)(r0p);
    float4 q0b = *(const float4*)(r0p + 4);
    float4 q1a = *(const float4*)(r1p);
    float4 q1b = *(const float4*)(r1p + 4);

    int w  = x >> 6;
    int wi = (b << 14) + (y << 4) + w;
    u64 tw = bits[wi];
    u64 fw = fore[wi];

    // inline 3x3 dilation of back skeleton at this word
    const u64* bb = back + (b << 14);
    int rbase = y << 4;
    u64 m0 = bb[rbase + w];
    u64 mL = w ? bb[rbase + w - 1] : 0ull;
    u64 mR = (w < 15) ? bb[rbase + w + 1] : 0ull;
    if (y > 0) {
        m0 |= bb[rbase - 16 + w];
        if (w) mL |= bb[rbase - 16 + w - 1];
        if (w < 15) mR |= bb[rbase - 16 + w + 1];
    }
    if (y < 1023) {
        m0 |= bb[rbase + 16 + w];
        if (w) mL |= bb[rbase + 16 + w - 1];
        if (w < 15) mR |= bb[rbase + 16 + w + 1];
    }
    u64 dil = m0 | (m0 << 1) | (mL >> 63) | (m0 >> 1) | (mR << 63);

    float c1 = s_c1;
    float c0 = (float)PIXELS_PER_IMG - c1;
    float mn = fminf(c0, c1);
    float rmn = __builtin_amdgcn_rcpf(mn);
    float w0 = c1 * rmn, w1 = c0 * rmn;   // class weight for class 0 / 1
    float factor = fminf((float)epochp[0] / 50.0f, 1.0f);

    int j0 = x & 63;                                // multiple of 8
    u32 t8 = (u32)(tw  >> j0) & 255u;
    u32 f8 = (u32)(fw  >> j0) & 255u;
    u32 b8 = (u32)(dil >> j0) & 255u;

    float p0v[8] = {q0a.x, q0a.y, q0a.z, q0a.w, q0b.x, q0b.y, q0b.z, q0b.w};
    float p1v[8] = {q1a.x, q1a.y, q1a.z, q1a.w, q1b.x, q1b.y, q1b.z, q1b.w};

    float acc = 0.f;
    #pragma unroll
    for (int i = 0; i < 8; ++i) {
        u32 tt = (t8 >> i) & 1u;
        float fb = (float)(((f8 >> i) & 1u) + ((b8 >> i) & 1u));
        float wmap = 1.0f + factor * fb;
        float cw = tt ? w1 : w0;
        float diff  = p1v[i] - p0v[i];
        float adiff = fabsf(diff);
        float T = LN2 * __builtin_amdgcn_logf(1.0f + __builtin_amdgcn_exp2f(-adiff * LOG2E));
        float ce = fmaf(tt ? -0.5f : 0.5f, diff, fmaf(0.5f, adiff, T));
        acc = fmaf(wmap * cw, ce, acc);
    }
    for (int off = 32; off; off >>= 1) acc += __shfl_down(acc, off, 64);
    __shared__ float wsum[4];
    if ((threadIdx.x & 63) == 0) wsum[threadIdx.x >> 6] = acc;
    __syncthreads();
    if (threadIdx.x == 0)
        partials[blockIdx.x] = wsum[0] + wsum[1] + wsum[2] + wsum[3];
}

// ---------------- K5: final reduce (8192 partials) ----------------
__global__ __launch_bounds__(256) void k_reduce(const float* __restrict__ partials,
                                                float* __restrict__ out) {
    double acc = 0.0;
    for (int i = threadIdx.x; i < 8192; i += 256) acc += (double)partials[i];
    for (int off = 32; off; off >>= 1) acc += __shfl_down(acc, off, 64);
    __shared__ double sd[4];
    if ((threadIdx.x & 63) == 0) sd[threadIdx.x >> 6] = acc;
    __syncthreads();
    if (threadIdx.x == 0)
        out[0] = (float)((sd[0] + sd[1] + sd[2] + sd[3]) / 16777216.0);
}

extern "C" void kernel_launch(void* const* d_in, const int* in_sizes, int n_in,
                              void* d_out, int out_size, void* d_ws, size_t ws_size,
                              hipStream_t stream) {
    const float* pred   = (const float*)d_in[0];
    const int*   target = (const int*)d_in[1];
    const int*   epoch  = (const int*)d_in[2];

    char* ws = (char*)d_ws;
    u32*   cpart    = (u32*)(ws + 1024);           // 16 KB
    float* partials = (float*)(ws + (1u << 17));   // 32 KB @ 128K
    u64*   bits     = (u64*)(ws + (1u << 20));     // 2 MB
    u64*   fore     = (u64*)(ws + (3u << 20));     // 2 MB
    u64*   back     = (u64*)(ws + (5u << 20));     // 2 MB

    hipLaunchKernelGGL(k_pack,   dim3(4096), dim3(256), 0, stream, target, bits, cpart);
    hipLaunchKernelGGL(k_skel,   dim3(512),  dim3(256), 0, stream, bits, fore, back);
    hipLaunchKernelGGL(k_loss,   dim3(8192), dim3(256), 0, stream, pred, bits, fore, back,
                       cpart, epoch, partials);
    hipLaunchKernelGGL(k_reduce, dim3(1),    dim3(256), 0, stream, partials, (float*)d_out);
}

// Round 5
// 58.399 us; speedup vs baseline: 14.7798x; 1.1337x over previous
//
#include <hip/hip_runtime.h>
#include <stdint.h>

typedef unsigned long long u64;
typedef unsigned int u32;
typedef unsigned short u16;

#define WPR 16                      // u64 words per 1024-px row
#define WORDS_PER_IMG (1024*WPR)    // 16384
#define PIXELS_PER_IMG (1024*1024)

// skeletonize strip geometry: 16 strips x 66 owned rows (covers 1024), 31-row halo
#define SOWN 66
#define SHALO 31
#define SROWS 128                   // SOWN + 2*SHALO
#define SPAD 17                     // padded LDS row stride (words) -> 2-way bank alias (free)

// ---------------- K2: bitpack target (16 px/thread, int4 loads) ----------------
__global__ __launch_bounds__(256) void k_pack(const int* __restrict__ tgt,
                                              u64* __restrict__ bits,
                                              u32* __restrict__ cpart) {
    __shared__ u16 marr[256];
    __shared__ u32 ws_[4];
    int t = threadIdx.x;
    const int4* p4 = (const int4*)(tgt + ((size_t)blockIdx.x * 256 + t) * 16);
    u32 m16 = 0;
    #pragma unroll
    for (int k = 0; k < 4; ++k) {
        int4 v = p4[k];
        m16 |= (u32)(v.x & 1) << (4 * k + 0);
        m16 |= (u32)(v.y & 1) << (4 * k + 1);
        m16 |= (u32)(v.z & 1) << (4 * k + 2);
        m16 |= (u32)(v.w & 1) << (4 * k + 3);
    }
    marr[t] = (u16)m16;
    u32 cnt = __popc(m16);
    for (int off = 32; off; off >>= 1) cnt += __shfl_down(cnt, off, 64);
    if ((t & 63) == 0) ws_[t >> 6] = cnt;
    __syncthreads();
    if (t < 64)
        bits[(size_t)blockIdx.x * 64 + t] = ((const u64*)marr)[t];
    if (t == 0) cpart[blockIdx.x] = ws_[0] + ws_[1] + ws_[2] + ws_[3];
}

// ---------------- K3: bitwise skeletonize v2 (register-resident rows) ----------------
// thread t: buffer row r = t>>1 (0..127), half h = t&1 -> words [8h, 8h+8)
// erode: read 3x10-word windows from LDS, compute 3x3 erode fully in regs, write 8 words
// dilate(open): read 3x10 windows of eroded, s |= orig & ~opened (owned rows only, no LDS write)
__global__ __launch_bounds__(256) void k_skel(const u64* __restrict__ bits,
                                              u64* __restrict__ fore,
                                              u64* __restrict__ back) {
    __shared__ u64 bufA[SROWS][SPAD];
    __shared__ u64 bufB[SROWS][SPAD];
    __shared__ int nzbuf[2];

    int bid   = blockIdx.x;
    int strip = bid & 15;
    int task  = bid >> 4;
    int batch = task >> 1;
    int pol   = task & 1;                 // 0 = fore (a), 1 = back (~a)
    int r0    = strip * SOWN - SHALO;     // y of buffer row 0
    const u64* img = bits + batch * WORDS_PER_IMG;

    int t  = threadIdx.x;
    int r  = t >> 1;
    int h  = t & 1;
    int w0 = h << 3;
    int y  = r0 + r;
    bool yok   = ((unsigned)y < 1024u);
    bool owned = yok && (r >= SHALO) && (r < SHALO + SOWN);

    u64 (*E)[SPAD]  = bufA;
    u64 (*Er)[SPAD] = bufB;

    // init: E rows (invalid y -> 0; erode substitutes via flags, dilate-neutral 0)
    if (yok) {
        const u64* src = img + (y << 4) + w0;
        #pragma unroll
        for (int k = 0; k < 8; ++k) {
            u64 v = src[k];
            E[r][w0 + k] = pol ? ~v : v;
        }
    } else {
        #pragma unroll
        for (int k = 0; k < 8; ++k) E[r][w0 + k] = 0;
    }
    if (t < 2) nzbuf[t] = 0;

    u64 s[8] = {0,0,0,0,0,0,0,0};
    u64 corig[8];

    // 10-word window loader; whole-row OOB (buffer edge or y-invalid) -> oob fill
    auto ldwin = [&](u64 (*B)[SPAD], int rr, u64 oob, u64* d) {
        int yy = r0 + rr;
        if (rr >= 0 && rr < SROWS && (unsigned)yy < 1024u) {
            d[0] = (w0 > 0) ? B[rr][w0 - 1] : oob;
            #pragma unroll
            for (int k = 0; k < 8; ++k) d[k + 1] = B[rr][w0 + k];
            d[9] = (w0 + 8 < 16) ? B[rr][w0 + 8] : oob;
        } else {
            #pragma unroll
            for (int k = 0; k < 10; ++k) d[k] = oob;
        }
    };
    #define HOR_E(d, k) (d[k] & ((d[k] << 1) | (d[k-1] >> 63)) & ((d[k] >> 1) | (d[k+1] << 63)))
    #define HOR_D(d, k) (d[k] | (d[k] << 1) | (d[k-1] >> 63) | (d[k] >> 1) | (d[k+1] << 63))

    __syncthreads();
    for (int it = 0; it < 32; ++it) {
        // ---- erode E -> Er (regs), detect emptiness ----
        u64 rm[10], rc[10], rp[10];
        ldwin(E, r - 1, ~0ull, rm);
        ldwin(E, r,     ~0ull, rc);
        ldwin(E, r + 1, ~0ull, rp);
        u64 any = 0;
        #pragma unroll
        for (int k = 0; k < 8; ++k) {
            u64 v = HOR_E(rm, k + 1) & HOR_E(rc, k + 1) & HOR_E(rp, k + 1);
            if (!yok) v = 0;
            any |= v;
            corig[k] = rc[k + 1];
            Er[r][w0 + k] = v;
        }
        u64 bal = __ballot(any != 0);
        if (bal && (t & 63) == 0) atomicOr(&nzbuf[it & 1], 1);
        if (t == 0) nzbuf[(it + 1) & 1] = 0;
        __syncthreads();
        if (nzbuf[it & 1] == 0) {
            // eroded strip empty: opened = 0 forever -> s |= e, stop
            if (owned) {
                #pragma unroll
                for (int k = 0; k < 8; ++k) s[k] |= corig[k];
            }
            break;
        }
        // ---- opened = dilate(Er); s |= orig & ~opened (owned rows only) ----
        if (owned) {
            u64 dm[10], dc[10], dp[10];
            ldwin(Er, r - 1, 0ull, dm);
            ldwin(Er, r,     0ull, dc);
            ldwin(Er, r + 1, 0ull, dp);
            #pragma unroll
            for (int k = 0; k < 8; ++k) {
                u64 op = HOR_D(dm, k + 1) | HOR_D(dc, k + 1) | HOR_D(dp, k + 1);
                s[k] |= corig[k] & ~op;
            }
        }
        { u64 (*tmp)[SPAD] = E; E = Er; Er = tmp; }
        __syncthreads();
    }

    if (owned) {
        u64* plane = (pol ? back : fore) + batch * WORDS_PER_IMG + (y << 4) + w0;
        #pragma unroll
        for (int k = 0; k < 8; ++k) plane[k] = s[k];
    }
    #undef HOR_E
    #undef HOR_D
}

// ---------------- K4: fused loss v2 (LDS-staged planes, 8 px/thread) ----------------
// block = 2 image rows (2048 px); stages bits/fore rows y0..y0+1 and back rows y0-1..y0+2,
// precomputes dilated-back words once, then per-thread work is pure register/LDS-broadcast.
__global__ __launch_bounds__(256) void k_loss(const float* __restrict__ pred,
                                              const u64* __restrict__ bits,
                                              const u64* __restrict__ fore,
                                              const u64* __restrict__ back,
                                              const u32* __restrict__ cpart,
                                              const int* __restrict__ epochp,
                                              float* __restrict__ partials) {
    const float LOG2E = 1.4426950408889634f;
    const float LN2   = 0.6931471805599453f;

    __shared__ u64 tb[2][16], tf[2][16], tbk[4][16], dil[2][16];
    __shared__ u32 cs[4];
    __shared__ float s_c1;
    __shared__ float wsum[4];

    int bid = blockIdx.x;
    int b   = bid >> 9;                    // 512 blocks per batch
    int rp  = bid & 511;
    int y0  = rp << 1;
    int t   = threadIdx.x;

    // batch one-count from k_pack partials (L2/L3-hit)
    u32 v = cpart[(b << 8) + t];
    for (int off = 32; off; off >>= 1) v += __shfl_down(v, off, 64);
    if ((t & 63) == 0) cs[t >> 6] = v;

    // stage bit-planes
    int base = b << 14;
    if (t < 32) {
        int i = t >> 4, w = t & 15;
        tb[i][w] = bits[base + ((y0 + i) << 4) + w];
    } else if (t < 64) {
        int tt = t - 32; int i = tt >> 4, w = tt & 15;
        tf[i][w] = fore[base + ((y0 + i) << 4) + w];
    } else if (t < 128) {
        int tt = t - 64; int i = tt >> 4, w = tt & 15;
        int yy = y0 - 1 + i;
        tbk[i][w] = ((unsigned)yy < 1024u) ? back[base + (yy << 4) + w] : 0ull;
    }
    __syncthreads();
    if (t < 32) {
        int i = t >> 4, w = t & 15;
        u64 m0 = tbk[i][w] | tbk[i + 1][w] | tbk[i + 2][w];
        u64 mL = (w > 0)  ? (tbk[i][w - 1] | tbk[i + 1][w - 1] | tbk[i + 2][w - 1]) : 0ull;
        u64 mR = (w < 15) ? (tbk[i][w + 1] | tbk[i + 1][w + 1] | tbk[i + 2][w + 1]) : 0ull;
        dil[i][w] = m0 | (m0 << 1) | (mL >> 63) | (m0 >> 1) | (mR << 63);
    }
    if (t == 0) s_c1 = (float)(cs[0] + cs[1] + cs[2] + cs[3]);
    __syncthreads();

    int ry = t >> 7;                // 0/1: which of the 2 rows
    int xq = t & 127;               // position within row (8-px chunks)
    int x  = xq << 3;
    int y  = y0 + ry;

    const float* pb  = pred + (size_t)b * (2 * PIXELS_PER_IMG);
    const float* r0p = pb + (y << 10) + x;
    const float* r1p = pb + PIXELS_PER_IMG + (y << 10) + x;
    float4 q0a = *(const float4*)(r0p);
    float4 q0b = *(const float4*)(r0p + 4);
    float4 q1a = *(const float4*)(r1p);
    float4 q1b = *(const float4*)(r1p + 4);

    int wq = xq >> 3;               // u64 word = x>>6
    u64 tw = tb[ry][wq];
    u64 fw = tf[ry][wq];
    u64 dl = dil[ry][wq];

    float c1 = s_c1;
    float c0 = (float)PIXELS_PER_IMG - c1;
    float mn = fminf(c0, c1);
    float rmn = __builtin_amdgcn_rcpf(mn);
    float w0 = c1 * rmn, w1 = c0 * rmn;
    float factor = fminf((float)epochp[0] / 50.0f, 1.0f);

    int j0 = (t & 7) << 3;
    u32 t8 = (u32)(tw >> j0) & 255u;
    u32 f8 = (u32)(fw >> j0) & 255u;
    u32 b8 = (u32)(dl >> j0) & 255u;

    float p0v[8] = {q0a.x, q0a.y, q0a.z, q0a.w, q0b.x, q0b.y, q0b.z, q0b.w};
    float p1v[8] = {q1a.x, q1a.y, q1a.z, q1a.w, q1b.x, q1b.y, q1b.z, q1b.w};

    float acc = 0.f;
    #pragma unroll
    for (int i = 0; i < 8; ++i) {
        u32 tt = (t8 >> i) & 1u;
        float fb = (float)(((f8 >> i) & 1u) + ((b8 >> i) & 1u));
        float wmap = 1.0f + factor * fb;
        float cw = tt ? w1 : w0;
        float diff  = p1v[i] - p0v[i];
        float adiff = fabsf(diff);
        float T = LN2 * __builtin_amdgcn_logf(1.0f + __builtin_amdgcn_exp2f(-adiff * LOG2E));
        float ce = fmaf(tt ? -0.5f : 0.5f, diff, fmaf(0.5f, adiff, T));
        acc = fmaf(wmap * cw, ce, acc);
    }
    for (int off = 32; off; off >>= 1) acc += __shfl_down(acc, off, 64);
    if ((t & 63) == 0) wsum[t >> 6] = acc;
    __syncthreads();
    if (t == 0)
        partials[bid] = wsum[0] + wsum[1] + wsum[2] + wsum[3];
}

// ---------------- K5: final reduce (8192 partials) ----------------
__global__ __launch_bounds__(256) void k_reduce(const float* __restrict__ partials,
                                                float* __restrict__ out) {
    double acc = 0.0;
    for (int i = threadIdx.x; i < 8192; i += 256) acc += (double)partials[i];
    for (int off = 32; off; off >>= 1) acc += __shfl_down(acc, off, 64);
    __shared__ double sd[4];
    if ((threadIdx.x & 63) == 0) sd[threadIdx.x >> 6] = acc;
    __syncthreads();
    if (threadIdx.x == 0)
        out[0] = (float)((sd[0] + sd[1] + sd[2] + sd[3]) / 16777216.0);
}

extern "C" void kernel_launch(void* const* d_in, const int* in_sizes, int n_in,
                              void* d_out, int out_size, void* d_ws, size_t ws_size,
                              hipStream_t stream) {
    const float* pred   = (const float*)d_in[0];
    const int*   target = (const int*)d_in[1];
    const int*   epoch  = (const int*)d_in[2];

    char* ws = (char*)d_ws;
    u32*   cpart    = (u32*)(ws + 1024);           // 16 KB
    float* partials = (float*)(ws + (1u << 17));   // 32 KB @ 128K
    u64*   bits     = (u64*)(ws + (1u << 20));     // 2 MB
    u64*   fore     = (u64*)(ws + (3u << 20));     // 2 MB
    u64*   back     = (u64*)(ws + (5u << 20));     // 2 MB

    hipLaunchKernelGGL(k_pack,   dim3(4096), dim3(256), 0, stream, target, bits, cpart);
    hipLaunchKernelGGL(k_skel,   dim3(512),  dim3(256), 0, stream, bits, fore, back);
    hipLaunchKernelGGL(k_loss,   dim3(8192), dim3(256), 0, stream, pred, bits, fore, back,
                       cpart, epoch, partials);
    hipLaunchKernelGGL(k_reduce, dim3(1),    dim3(256), 0, stream, partials, (float*)d_out);
}